// Round 3
// baseline (2003.040 us; speedup 1.0000x reference)
//
#include <hip/hip_runtime.h>
#include <stdint.h>

#define B_TRAJ  4096
#define H_DIM   100
#define T_STEPS 100
#define ROWS    16
#define NBLK    256
#define THREADS 1024

typedef float    f32x4  __attribute__((ext_vector_type(4)));
typedef __bf16   bf16x8 __attribute__((ext_vector_type(8)));
typedef uint16_t u16x8  __attribute__((ext_vector_type(8)));

// ---- packed-weight layout in d_ws (u16/bf16 elements) ----
// within a pack: idx = (kt*N + n)*32 + kk ; kk = g*8 + e maps k = kt*32+kk
#define OFF_P0F  0        // [4][256][32]  W0[n][k]  (K pad 128)
#define OFF_P1F  32768    // [8][256][32]  W1[n][k]
#define OFF_P2F  98304
#define OFF_P3F  163840
#define OFF_P1B  229376   // [8][256][32]  W1[k][n]
#define OFF_P2B  294912
#define OFF_P3B  360448
#define OFF_P0B  425984   // [8][128][32]  W0[k][1+n] (N pad 128)
#define OFF_W4P  458752   // [256] bf16 W4 linear
#define OFF_KEYS 459008   // 200 x u32 (as 400 u16 slots)
#define PACK_TOTAL 459008
#define PACK_GRID ((PACK_TOTAL + 255) / 256)

__device__ __forceinline__ uint16_t f2bf(float f) {
  uint32_t u = __float_as_uint(f);
  uint32_t r = u + 0x7FFFu + ((u >> 16) & 1u);   // RNE
  return (uint16_t)(r >> 16);
}
__device__ __forceinline__ float bf2f(uint16_t u) {
  return __uint_as_float(((uint32_t)u) << 16);
}
__device__ __forceinline__ uint32_t rotl32(uint32_t v, int d) {
  return (v << d) | (v >> (32 - d));
}

// JAX Threefry-2x32, 20 rounds, exact key schedule.
__device__ __forceinline__ void threefry2x32(uint32_t k0, uint32_t k1,
                                             uint32_t x0, uint32_t x1,
                                             uint32_t& o0, uint32_t& o1) {
  const uint32_t k2 = k0 ^ k1 ^ 0x1BD11BDAu;
  x0 += k0; x1 += k1;
  x0 += x1; x1 = rotl32(x1, 13); x1 ^= x0;
  x0 += x1; x1 = rotl32(x1, 15); x1 ^= x0;
  x0 += x1; x1 = rotl32(x1, 26); x1 ^= x0;
  x0 += x1; x1 = rotl32(x1,  6); x1 ^= x0;
  x0 += k1; x1 += k2 + 1u;
  x0 += x1; x1 = rotl32(x1, 17); x1 ^= x0;
  x0 += x1; x1 = rotl32(x1, 29); x1 ^= x0;
  x0 += x1; x1 = rotl32(x1, 16); x1 ^= x0;
  x0 += x1; x1 = rotl32(x1, 24); x1 ^= x0;
  x0 += k2; x1 += k0 + 2u;
  x0 += x1; x1 = rotl32(x1, 13); x1 ^= x0;
  x0 += x1; x1 = rotl32(x1, 15); x1 ^= x0;
  x0 += x1; x1 = rotl32(x1, 26); x1 ^= x0;
  x0 += x1; x1 = rotl32(x1,  6); x1 ^= x0;
  x0 += k0; x1 += k1 + 3u;
  x0 += x1; x1 = rotl32(x1, 17); x1 ^= x0;
  x0 += x1; x1 = rotl32(x1, 29); x1 ^= x0;
  x0 += x1; x1 = rotl32(x1, 16); x1 ^= x0;
  x0 += x1; x1 = rotl32(x1, 24); x1 ^= x0;
  x0 += k1; x1 += k2 + 4u;
  x0 += x1; x1 = rotl32(x1, 13); x1 ^= x0;
  x0 += x1; x1 = rotl32(x1, 15); x1 ^= x0;
  x0 += x1; x1 = rotl32(x1, 26); x1 ^= x0;
  x0 += x1; x1 = rotl32(x1,  6); x1 ^= x0;
  x0 += k2; x1 += k0 + 5u;
  o0 = x0; o1 = x1;
}

// XLA ErfInv32 (Giles)
__device__ __forceinline__ float erfinv_f32(float x) {
  float w = -log1pf(-x * x);
  float p;
  if (w < 5.0f) {
    w = w - 2.5f;
    p = 2.81022636e-08f;
    p = fmaf(p, w, 3.43273939e-07f);
    p = fmaf(p, w, -3.5233877e-06f);
    p = fmaf(p, w, -4.39150654e-06f);
    p = fmaf(p, w, 0.00021858087f);
    p = fmaf(p, w, -0.00125372503f);
    p = fmaf(p, w, -0.00417768164f);
    p = fmaf(p, w, 0.246640727f);
    p = fmaf(p, w, 1.50140941f);
  } else {
    w = sqrtf(w) - 3.0f;
    p = -0.000200214257f;
    p = fmaf(p, w, 0.000100950558f);
    p = fmaf(p, w, 0.00134934322f);
    p = fmaf(p, w, -0.00367342844f);
    p = fmaf(p, w, 0.00573950773f);
    p = fmaf(p, w, -0.0076224613f);
    p = fmaf(p, w, 0.00943887047f);
    p = fmaf(p, w, 1.00167406f);
    p = fmaf(p, w, 2.83297682f);
  }
  return p * x;
}

// ---------------- weight packing + key chain (once per launch) ----------------
__global__ __launch_bounds__(256) void pack_kernel(
    const float* __restrict__ W0, const float* __restrict__ W1,
    const float* __restrict__ W2, const float* __restrict__ W3,
    const float* __restrict__ W4, uint16_t* __restrict__ P) {
  const int i = blockIdx.x * 256 + threadIdx.x;
  if (i == 0) {  // serial key chain: key(42), per step use child0, carry child1
    uint32_t* K = (uint32_t*)(P + OFF_KEYS);
    uint32_t c0 = 0u, c1 = 42u;
    for (int s = 0; s < T_STEPS; ++s) {
      uint32_t a0_, a1_, n0, n1;
      threefry2x32(c0, c1, 0u, 0u, a0_, a1_);
      threefry2x32(c0, c1, 0u, 1u, n0, n1);
      K[2 * s] = a0_; K[2 * s + 1] = a1_;
      c0 = n0; c1 = n1;
    }
  }
  if (i >= PACK_TOTAL) return;
  float v;
  if (i < OFF_P1F) {                 // P0F
    int e = i - OFF_P0F;
    int kk = e & 31, n = (e >> 5) & 255, kt = e >> 13;
    int k = kt * 32 + kk;
    v = (k < 101) ? W0[n * 101 + k] : 0.0f;
  } else if (i < OFF_P2F) {          // P1F
    int e = i - OFF_P1F;
    int kk = e & 31, n = (e >> 5) & 255, kt = e >> 13;
    v = W1[n * 256 + kt * 32 + kk];
  } else if (i < OFF_P3F) {          // P2F
    int e = i - OFF_P2F;
    int kk = e & 31, n = (e >> 5) & 255, kt = e >> 13;
    v = W2[n * 256 + kt * 32 + kk];
  } else if (i < OFF_P1B) {          // P3F
    int e = i - OFF_P3F;
    int kk = e & 31, n = (e >> 5) & 255, kt = e >> 13;
    v = W3[n * 256 + kt * 32 + kk];
  } else if (i < OFF_P2B) {          // P1B
    int e = i - OFF_P1B;
    int kk = e & 31, n = (e >> 5) & 255, kt = e >> 13;
    v = W1[(kt * 32 + kk) * 256 + n];
  } else if (i < OFF_P3B) {          // P2B
    int e = i - OFF_P2B;
    int kk = e & 31, n = (e >> 5) & 255, kt = e >> 13;
    v = W2[(kt * 32 + kk) * 256 + n];
  } else if (i < OFF_P0B) {          // P3B
    int e = i - OFF_P3B;
    int kk = e & 31, n = (e >> 5) & 255, kt = e >> 13;
    v = W3[(kt * 32 + kk) * 256 + n];
  } else if (i < OFF_W4P) {          // P0B
    int e = i - OFF_P0B;
    int kk = e & 31, n = (e >> 5) & 127, kt = e >> 12;
    int k = kt * 32 + kk;
    v = (n < 100) ? W0[k * 101 + 1 + n] : 0.0f;
  } else {                           // W4P
    v = W4[i - OFF_W4P];
  }
  P[i] = f2bf(v);
}

// ---------------- LDS ----------------
struct SmemT {
  uint16_t actI[ROWS][136];   // MLP input, K padded to 128
  uint16_t act1[ROWS][264];
  uint16_t act2[ROWS][264];
  uint16_t act3[ROWS][264];
  uint16_t act4[ROWS][264];
  uint16_t dpA[ROWS][264];
  uint16_t dpB[ROWS][264];
  float x_s[ROWS * H_DIM];
  float z_s[ROWS * H_DIM];
  float dw_s[ROWS * H_DIM];
  float y_s[ROWS];
  uint32_t keyA[T_STEPS], keyB[T_STEPS];
};

// ---------------- GEMM pieces ----------------
// MFMA 16x16x32 bf16. D[r][c]: r=(lane>>4)*4+reg, c=lane&15 (m89-verified).
// A[r][kslot]: r=lane&15; B[kslot][c]: c=lane&15. kslot=(g,e) packing is the
// same on both operands so any HW k-permutation cancels.

template<int KT, int INS>
__device__ __forceinline__ void gemm_fwd(const uint16_t (*in)[INS],
                                         const uint16_t* __restrict__ P,
                                         const float* __restrict__ bias,
                                         uint16_t (*outb)[264],
                                         int wave, int lane) {
  const int row16 = lane & 15, g = lane >> 4;
  const int c = row16 + 16 * wave;
  bf16x8 bfr[KT], afr[KT];
#pragma unroll
  for (int kt = 0; kt < KT; ++kt)
    bfr[kt] = *reinterpret_cast<const bf16x8*>(&P[(kt * 256 + c) * 32 + g * 8]);
#pragma unroll
  for (int kt = 0; kt < KT; ++kt)
    afr[kt] = *reinterpret_cast<const bf16x8*>(&in[row16][kt * 32 + g * 8]);
  const float bv = bias[c];
  f32x4 acc = {bv, bv, bv, bv};
#pragma unroll
  for (int kt = 0; kt < KT; ++kt)
    acc = __builtin_amdgcn_mfma_f32_16x16x32_bf16(afr[kt], bfr[kt], acc, 0, 0, 0);
#pragma unroll
  for (int reg = 0; reg < 4; ++reg)
    outb[g * 4 + reg][c] = f2bf(fmaxf(acc[reg], 0.0f));
}

__device__ __forceinline__ void gemm_bwd(const uint16_t (*in)[264],
                                         const uint16_t* __restrict__ P,
                                         const uint16_t (*mact)[264],
                                         uint16_t (*outb)[264],
                                         int wave, int lane) {
  const int row16 = lane & 15, g = lane >> 4;
  const int c = row16 + 16 * wave;
  bf16x8 bfr[8], afr[8];
#pragma unroll
  for (int kt = 0; kt < 8; ++kt)
    bfr[kt] = *reinterpret_cast<const bf16x8*>(&P[(kt * 256 + c) * 32 + g * 8]);
#pragma unroll
  for (int kt = 0; kt < 8; ++kt)
    afr[kt] = *reinterpret_cast<const bf16x8*>(&in[row16][kt * 32 + g * 8]);
  f32x4 acc = {0.f, 0.f, 0.f, 0.f};
#pragma unroll
  for (int kt = 0; kt < 8; ++kt)
    acc = __builtin_amdgcn_mfma_f32_16x16x32_bf16(afr[kt], bfr[kt], acc, 0, 0, 0);
#pragma unroll
  for (int reg = 0; reg < 4; ++reg) {
    const int r = g * 4 + reg;
    outb[r][c] = mact[r][c] ? f2bf(acc[reg]) : (uint16_t)0;
  }
}

// bwd3 with on-the-fly dp4 = (act4!=0 ? W4 : 0); no dp4 LDS round trip.
__device__ __forceinline__ void gemm_bwd3(const uint16_t (*act4)[264],
                                          const uint16_t* __restrict__ P,
                                          const uint16_t* __restrict__ W4P,
                                          const uint16_t (*mact)[264],
                                          uint16_t (*outb)[264],
                                          int wave, int lane) {
  const int row16 = lane & 15, g = lane >> 4;
  const int c = row16 + 16 * wave;
  bf16x8 bfr[8], afr[8];
#pragma unroll
  for (int kt = 0; kt < 8; ++kt)
    bfr[kt] = *reinterpret_cast<const bf16x8*>(&P[(kt * 256 + c) * 32 + g * 8]);
#pragma unroll
  for (int kt = 0; kt < 8; ++kt) {
    u16x8 au = *reinterpret_cast<const u16x8*>(&act4[row16][kt * 32 + g * 8]);
    u16x8 wu = *reinterpret_cast<const u16x8*>(&W4P[kt * 32 + g * 8]);
    u16x8 sel;
#pragma unroll
    for (int e = 0; e < 8; ++e) sel[e] = au[e] ? wu[e] : (uint16_t)0;
    afr[kt] = __builtin_bit_cast(bf16x8, sel);
  }
  f32x4 acc = {0.f, 0.f, 0.f, 0.f};
#pragma unroll
  for (int kt = 0; kt < 8; ++kt)
    acc = __builtin_amdgcn_mfma_f32_16x16x32_bf16(afr[kt], bfr[kt], acc, 0, 0, 0);
#pragma unroll
  for (int reg = 0; reg < 4; ++reg) {
    const int r = g * 4 + reg;
    outb[r][c] = mact[r][c] ? f2bf(acc[reg]) : (uint16_t)0;
  }
}

// z = dp1 @ P0B (waves 0..7, N=128 pad, fp32 out)
__device__ __forceinline__ void gemm_bwd0(const uint16_t (*in)[264],
                                          const uint16_t* __restrict__ P,
                                          float* __restrict__ z_s,
                                          int wave, int lane) {
  if (wave >= 8) return;
  const int row16 = lane & 15, g = lane >> 4;
  const int c = row16 + 16 * wave;
  bf16x8 bfr[8], afr[8];
#pragma unroll
  for (int kt = 0; kt < 8; ++kt)
    bfr[kt] = *reinterpret_cast<const bf16x8*>(&P[(kt * 128 + c) * 32 + g * 8]);
#pragma unroll
  for (int kt = 0; kt < 8; ++kt)
    afr[kt] = *reinterpret_cast<const bf16x8*>(&in[row16][kt * 32 + g * 8]);
  f32x4 acc = {0.f, 0.f, 0.f, 0.f};
#pragma unroll
  for (int kt = 0; kt < 8; ++kt)
    acc = __builtin_amdgcn_mfma_f32_16x16x32_bf16(afr[kt], bfr[kt], acc, 0, 0, 0);
  if (c < H_DIM) {
#pragma unroll
    for (int reg = 0; reg < 4; ++reg)
      z_s[(g * 4 + reg) * H_DIM + c] = acc[reg];
  }
}

// Full MLP fwd + VJP. Entry: actI ready + barrier done. Exit: barrier done.
__device__ void mlp_eval(SmemT& sm,
                         const uint16_t* __restrict__ P,
                         const float* __restrict__ b0, const float* __restrict__ b1,
                         const float* __restrict__ b2, const float* __restrict__ b3,
                         const float* __restrict__ W4, const float* __restrict__ b4,
                         float* __restrict__ ys_out, int row0,
                         int wave, int lane) {
  gemm_fwd<4, 136>(sm.actI, P + OFF_P0F, b0, sm.act1, wave, lane);
  __syncthreads();
  gemm_fwd<8, 264>(sm.act1, P + OFF_P1F, b1, sm.act2, wave, lane);
  __syncthreads();
  gemm_fwd<8, 264>(sm.act2, P + OFF_P2F, b2, sm.act3, wave, lane);
  __syncthreads();
  gemm_fwd<8, 264>(sm.act3, P + OFF_P3F, b3, sm.act4, wave, lane);
  __syncthreads();

  // y-reduction (wave w owns row w) fused with bwd3
  {
    float s = 0.0f;
#pragma unroll
    for (int m = 0; m < 4; ++m) {
      const int j = lane + (m << 6);
      s += bf2f(sm.act4[wave][j]) * W4[j];
    }
#pragma unroll
    for (int off = 32; off >= 1; off >>= 1) s += __shfl_xor(s, off, 64);
    if (lane == 0) {
      const float yv = s + b4[0];
      sm.y_s[wave] = yv;
      if (ys_out) ys_out[row0 + wave] = yv;
    }
  }
  gemm_bwd3(sm.act4, P + OFF_P3B, (const uint16_t*)(P + OFF_W4P),
            sm.act3, sm.dpA, wave, lane);
  __syncthreads();
  gemm_bwd(sm.dpA, P + OFF_P2B, sm.act2, sm.dpB, wave, lane);
  __syncthreads();
  gemm_bwd(sm.dpB, P + OFF_P1B, sm.act1, sm.dpA, wave, lane);
  __syncthreads();
  gemm_bwd0(sm.dpA, P + OFF_P0B, sm.z_s, wave, lane);
  __syncthreads();
}

__global__ __launch_bounds__(THREADS, 4) void fbsde_kernel(
    const float* __restrict__ x0, const float* __restrict__ t0p,
    const float* __restrict__ dtp,
    const float* __restrict__ b0, const float* __restrict__ b1,
    const float* __restrict__ b2, const float* __restrict__ b3,
    const float* __restrict__ W4, const float* __restrict__ b4,
    const uint16_t* __restrict__ P, float* __restrict__ out) {
  __shared__ __align__(16) SmemT sm;

  const int tid = threadIdx.x;
  const int wave = tid >> 6, lane = tid & 63;
  const int blk = blockIdx.x;
  const int row0 = blk * ROWS;

  // init: keys from pack, x_s, actI (t=0 col, x cols, zero pad)
  if (tid < T_STEPS) {
    const uint32_t* K = (const uint32_t*)(P + OFF_KEYS);
    sm.keyA[tid] = K[2 * tid];
    sm.keyB[tid] = K[2 * tid + 1];
  }
  for (int e = tid; e < ROWS * H_DIM; e += THREADS)
    sm.x_s[e] = x0[row0 * H_DIM + e];
  for (int e = tid; e < ROWS * 136; e += THREADS) {
    const int r = e / 136, cc = e - r * 136;
    uint16_t v = 0;
    if (cc >= 1 && cc <= H_DIM) v = f2bf(x0[(row0 + r) * H_DIM + cc - 1]);
    sm.actI[r][cc] = v;   // cc==0 -> t=0.0 -> bf16 0
  }
  const float t0v = t0p[0];
  const float dtv = dtp[0];
  const float sqdt = sqrtf(dtv);
  __syncthreads();

  float* const out_xfin = out;                                  // (B,H)
  float* const out_yfin = out + 409600;                         // (B,1)
  float* const out_zfin = out + 413696;                         // (B,H)
  float* const out_xs   = out + 823296;                         // (T,B,H)
  float* const out_yt   = out + 823296 + 40960000;              // (T,B,1)
  float* const out_ys   = out + 823296 + 40960000 + 409600;     // (T,B,1)

  mlp_eval(sm, P, b0, b1, b2, b3, W4, b4, nullptr, row0, wave, lane);

  for (int s = 0; s < T_STEPS; ++s) {
    // ---- PRNG: dW for this step ----
    const uint32_t ka = sm.keyA[s], kb = sm.keyB[s];
    for (int e = tid; e < ROWS * H_DIM; e += THREADS) {
      const uint32_t f = (uint32_t)(blk * (ROWS * H_DIM) + e);
      uint32_t o0, o1;
      threefry2x32(ka, kb, 0u, f, o0, o1);
      const uint32_t bits = o0 ^ o1;
      const float fr = __uint_as_float((bits >> 9) | 0x3F800000u) - 1.0f;
      const float minv = -0.99999994f;  // nextafter(-1, 0)
      const float u = fmaxf(fr * 2.0f + minv, minv);
      const float n = 1.41421354f * erfinv_f32(u);
      sm.dw_s[e] = n * sqdt;
    }
    __syncthreads();

    // ---- y_tilde + x-update + next actI, wave w owns row w ----
    const float tv = t0v + (float)(s + 1) * dtv;
    {
      const int base = wave * H_DIM;
      const int h0 = lane;                 // always < 100
      const int h1 = lane + 64;            // valid if < 100
      const float xv0 = sm.x_s[base + h0];
      const float zv0 = sm.z_s[base + h0];
      const float dw0 = sm.dw_s[base + h0];
      float s1 = xv0 * zv0;
      float s2 = zv0 * (0.4f * xv0) * dw0;
      float xv1 = 0.f, dw1 = 0.f;
      if (h1 < H_DIM) {
        xv1 = sm.x_s[base + h1];
        const float zv1 = sm.z_s[base + h1];
        dw1 = sm.dw_s[base + h1];
        s1 += xv1 * zv1;
        s2 += zv1 * (0.4f * xv1) * dw1;
      }
#pragma unroll
      for (int off = 32; off >= 1; off >>= 1) {
        s1 += __shfl_xor(s1, off, 64);
        s2 += __shfl_xor(s2, off, 64);
      }
      if (lane == 0) {
        const float yv = sm.y_s[wave];
        const float phi = 0.05f * (yv - s1);
        out_yt[(size_t)s * B_TRAJ + row0 + wave] = yv + phi * dtv + s2;
        sm.actI[wave][0] = f2bf(tv);
      }
      // x update (same lanes own the same elements: no cross-thread hazard)
      {
        const float x1 = xv0 + (0.4f * xv0) * dw0;
        sm.x_s[base + h0] = x1;
        sm.actI[wave][1 + h0] = f2bf(x1);
        out_xs[(size_t)s * (B_TRAJ * H_DIM) + (size_t)(row0 + wave) * H_DIM + h0] = x1;
        if (h1 < H_DIM) {
          const float x1b = xv1 + (0.4f * xv1) * dw1;
          sm.x_s[base + h1] = x1b;
          sm.actI[wave][1 + h1] = f2bf(x1b);
          out_xs[(size_t)s * (B_TRAJ * H_DIM) + (size_t)(row0 + wave) * H_DIM + h1] = x1b;
        }
      }
    }
    __syncthreads();

    mlp_eval(sm, P, b0, b1, b2, b3, W4, b4,
             out_ys + (size_t)s * B_TRAJ, row0, wave, lane);
  }

  for (int e = tid; e < ROWS * H_DIM; e += THREADS) {
    out_xfin[(size_t)row0 * H_DIM + e] = sm.x_s[e];
    out_zfin[(size_t)row0 * H_DIM + e] = sm.z_s[e];
  }
  if (tid < ROWS) out_yfin[row0 + tid] = sm.y_s[tid];
}

extern "C" void kernel_launch(void* const* d_in, const int* in_sizes, int n_in,
                              void* d_out, int out_size, void* d_ws, size_t ws_size,
                              hipStream_t stream) {
  (void)in_sizes; (void)n_in; (void)ws_size; (void)out_size;
  const float* x0 = (const float*)d_in[0];
  const float* t0 = (const float*)d_in[1];
  const float* dt = (const float*)d_in[2];
  const float* W0 = (const float*)d_in[4];
  const float* b0 = (const float*)d_in[5];
  const float* W1 = (const float*)d_in[6];
  const float* b1 = (const float*)d_in[7];
  const float* W2 = (const float*)d_in[8];
  const float* b2 = (const float*)d_in[9];
  const float* W3 = (const float*)d_in[10];
  const float* b3 = (const float*)d_in[11];
  const float* W4 = (const float*)d_in[12];
  const float* b4 = (const float*)d_in[13];
  uint16_t* P = (uint16_t*)d_ws;
  float* out = (float*)d_out;

  hipLaunchKernelGGL(pack_kernel, dim3(PACK_GRID), dim3(256), 0, stream,
                     W0, W1, W2, W3, W4, P);
  hipLaunchKernelGGL(fbsde_kernel, dim3(NBLK), dim3(THREADS), 0, stream,
                     x0, t0, dt, b0, b1, b2, b3, W4, b4, P, out);
}